// Round 1
// baseline (473.013 us; speedup 1.0000x reference)
//
#include <hip/hip_runtime.h>

#define HW 192
#define DD 512
#define GG 64
#define PP 64

typedef __attribute__((ext_vector_type(8))) short short8_t;
typedef __attribute__((ext_vector_type(4))) float floatx4;

typedef __attribute__((address_space(3))) unsigned int lds_u32;
typedef const __attribute__((address_space(1))) unsigned int glb_u32;

__device__ __forceinline__ void gload_lds16(const void* g, void* l) {
  __builtin_amdgcn_global_load_lds((glb_u32*)g, (lds_u32*)l, 16, 0, 0);
}

__device__ __forceinline__ unsigned short f2bf(float f) {
  unsigned int u = __float_as_uint(f);
  u += 0x7fffu + ((u >> 16) & 1u);
  return (unsigned short)(u >> 16);
}

// L2-normalize over channel dim and write transposed bf16: out[s][pos][c] = in[s][c][pos]/norm
// Blocks 0..63: gal -> galt slabs; 64..127: prob -> kern slabs.
__global__ __launch_bounds__(384) void norm_kernel(
    const float* __restrict__ gal, const float* __restrict__ prob,
    unsigned short* __restrict__ ws) {
  int b = blockIdx.x;
  const float* in = (b < GG) ? (gal + (size_t)b * DD * HW)
                             : (prob + (size_t)(b - GG) * DD * HW);
  unsigned short* out = ws + (size_t)b * DD * HW;
  int t = threadIdx.x;
  int half = t / HW;        // 0 or 1
  int pos = t - half * HW;  // 0..191

  __shared__ float ssq_l[384];
  __shared__ float scale_l[HW];

  float ssq = 0.f;
#pragma unroll 8
  for (int k = 0; k < DD / 2; ++k) {
    float x = in[(size_t)(2 * k + half) * HW + pos];
    ssq += x * x;
  }
  ssq_l[t] = ssq;
  __syncthreads();
  if (t < HW) {
    float s = ssq_l[t] + ssq_l[t + HW];
    float n = sqrtf(s);
    scale_l[t] = 1.f / fmaxf(n, 1e-12f);
  }
  __syncthreads();
  // write transposed: element e = pos*512 + c (c fastest -> coalesced writes)
#pragma unroll 4
  for (int k = 0; k < 256; ++k) {
    int e = k * 384 + t;
    int c = e & (DD - 1);
    int ps = e >> 9;
    float v = in[(size_t)c * HW + ps] * scale_l[ps];
    out[e] = f2bf(v);
  }
}

// One block per (g,p): C[i][j] = sum_d kern[p][i][d]*galt[g][j][d], fused dual max + BN/fc/lbn/sigmoid.
__global__ __launch_bounds__(256, 2) void qaconv_gemm(
    const unsigned short* __restrict__ ws, const float* __restrict__ fcw,
    const float* __restrict__ bnw, const float* __restrict__ bnb,
    const float* __restrict__ bnm, const float* __restrict__ bnv,
    const float* __restrict__ fcb, const float* __restrict__ lw,
    const float* __restrict__ lb, const float* __restrict__ lm,
    const float* __restrict__ lv, float* __restrict__ out) {
  int bid = blockIdx.x;
  int sb = bid >> 6, li = bid & 63;           // 8x8 supertiles for L2 locality
  int g = ((sb >> 3) << 3) + (li >> 3);
  int p = ((sb & 7) << 3) + (li & 7);
  const unsigned short* Bsrc = ws + (size_t)g * DD * HW;         // galt[g][j][c]
  const unsigned short* Asrc = ws + (size_t)(GG + p) * DD * HW;  // kern[p][i][c]

  // LDS tile layout: chunk n = kc*192 + row, 16B per chunk -> [kc(4)][row(192)][8 bf16]
  __shared__ unsigned short A_lds[768 * 8];  // 12 KB
  __shared__ unsigned short B_lds[768 * 8];  // 12 KB
  __shared__ float colpart[2][HW];
  __shared__ float rowpart[2][HW];
  __shared__ float redbuf[4][2];

  int tid = threadIdx.x;
  int lane = tid & 63;
  int wave = tid >> 6;
  int wi = wave >> 1, wj = wave & 1;  // wave covers rows wi*96..+96, cols wj*96..+96
  int l15 = lane & 15, l4 = lane >> 4;

  floatx4 acc[6][6];
#pragma unroll
  for (int a = 0; a < 6; ++a)
#pragma unroll
    for (int c = 0; c < 6; ++c) acc[a][c] = (floatx4){0.f, 0.f, 0.f, 0.f};

  for (int kb = 0; kb < DD / 32; ++kb) {
    // stage A and B tiles: 768 16B-chunks each, 256 threads x 3 iters
#pragma unroll
    for (int s = 0; s < 3; ++s) {
      int n = tid + s * 256;
      int kc = n / HW;
      int row = n - kc * HW;
      size_t goff = (size_t)row * DD + (size_t)(kb * 32 + kc * 8);
      gload_lds16(Asrc + goff, &A_lds[n * 8]);
      gload_lds16(Bsrc + goff, &B_lds[n * 8]);
    }
    __syncthreads();

    short8_t a[6];
#pragma unroll
    for (int it = 0; it < 6; ++it)
      a[it] = *(const short8_t*)&A_lds[(l4 * HW + wi * 96 + it * 16 + l15) * 8];
#pragma unroll
    for (int jt = 0; jt < 6; ++jt) {
      short8_t b = *(const short8_t*)&B_lds[(l4 * HW + wj * 96 + jt * 16 + l15) * 8];
#pragma unroll
      for (int it = 0; it < 6; ++it)
        acc[it][jt] = __builtin_amdgcn_mfma_f32_16x16x32_bf16(a[it], b, acc[it][jt], 0, 0, 0);
    }
    __syncthreads();
  }

  // ---- epilogue: dual max-pool ----
  // C/D layout: i = wi*96 + it*16 + l4*4 + r ; j = wj*96 + jt*16 + l15
  float cm[6];
  float rm[6][4];
#pragma unroll
  for (int jt = 0; jt < 6; ++jt) cm[jt] = -3.4e38f;
#pragma unroll
  for (int it = 0; it < 6; ++it)
#pragma unroll
    for (int r = 0; r < 4; ++r) rm[it][r] = -3.4e38f;
#pragma unroll
  for (int it = 0; it < 6; ++it)
#pragma unroll
    for (int jt = 0; jt < 6; ++jt)
#pragma unroll
      for (int r = 0; r < 4; ++r) {
        float v = acc[it][jt][r];
        cm[jt] = fmaxf(cm[jt], v);
        rm[it][r] = fmaxf(rm[it][r], v);
      }

  // colmax: reduce across lanes differing in bits 4,5 (same col, different rows)
#pragma unroll
  for (int jt = 0; jt < 6; ++jt) {
    float v = cm[jt];
    v = fmaxf(v, __shfl_xor(v, 16, 64));
    v = fmaxf(v, __shfl_xor(v, 32, 64));
    if (lane < 16) colpart[wi][wj * 96 + jt * 16 + lane] = v;
  }
  // rowmax: reduce across lanes differing in bits 0..3 (same rows, different cols)
#pragma unroll
  for (int it = 0; it < 6; ++it)
#pragma unroll
    for (int r = 0; r < 4; ++r) {
      float v = rm[it][r];
      v = fmaxf(v, __shfl_xor(v, 1, 64));
      v = fmaxf(v, __shfl_xor(v, 2, 64));
      v = fmaxf(v, __shfl_xor(v, 4, 64));
      v = fmaxf(v, __shfl_xor(v, 8, 64));
      if (l15 == 0) rowpart[wj][wi * 96 + it * 16 + l4 * 4 + r] = v;
    }
  __syncthreads();

  // ---- fused BN -> fc -> lbn -> sigmoid ----
  float part = 0.f, wpart = 0.f;
  if (tid < HW) {
    float cmax = fmaxf(colpart[0][tid], colpart[1][tid]);  // score[j], j=tid
    float rmax = fmaxf(rowpart[0][tid], rowpart[1][tid]);  // score[192+i], i=tid
    float w1 = fcw[tid], w2 = fcw[HW + tid];
    part = cmax * w1 + rmax * w2;
    wpart = w1 + w2;
  }
#pragma unroll
  for (int off = 32; off > 0; off >>= 1) {
    part += __shfl_down(part, off, 64);
    wpart += __shfl_down(wpart, off, 64);
  }
  if (lane == 0) { redbuf[wave][0] = part; redbuf[wave][1] = wpart; }
  __syncthreads();
  if (tid == 0) {
    float s = redbuf[0][0] + redbuf[1][0] + redbuf[2][0] + redbuf[3][0];
    float wsum = redbuf[0][1] + redbuf[1][1] + redbuf[2][1] + redbuf[3][1];
    float bnA = bnw[0] * rsqrtf(bnv[0] + 1e-5f);
    float bnB = bnb[0] - bnm[0] * bnA;
    float sc = bnA * s + bnB * wsum + fcb[0];
    float lA = lw[0] * rsqrtf(lv[0] + 1e-5f);
    sc = (sc - lm[0]) * lA + lb[0];
    out[g * PP + p] = 1.f / (1.f + __expf(-sc * 0.1f));
  }
}

extern "C" void kernel_launch(void* const* d_in, const int* in_sizes, int n_in,
                              void* d_out, int out_size, void* d_ws, size_t ws_size,
                              hipStream_t stream) {
  const float* gal  = (const float*)d_in[0];
  const float* prob = (const float*)d_in[1];
  const float* bnw  = (const float*)d_in[2];
  const float* bnb  = (const float*)d_in[3];
  const float* bnm  = (const float*)d_in[4];
  const float* bnv  = (const float*)d_in[5];
  const float* fcw  = (const float*)d_in[6];
  const float* fcb  = (const float*)d_in[7];
  const float* lw   = (const float*)d_in[8];
  const float* lb   = (const float*)d_in[9];
  const float* lm   = (const float*)d_in[10];
  const float* lv   = (const float*)d_in[11];
  unsigned short* ws = (unsigned short*)d_ws;
  float* out = (float*)d_out;

  hipLaunchKernelGGL(norm_kernel, dim3(128), dim3(384), 0, stream, gal, prob, ws);
  hipLaunchKernelGGL(qaconv_gemm, dim3(GG * PP), dim3(256), 0, stream, ws, fcw,
                     bnw, bnb, bnm, bnv, fcb, lw, lb, lm, lv, out);
}

// Round 2
// 441.061 us; speedup vs baseline: 1.0724x; 1.0724x over previous
//
#include <hip/hip_runtime.h>

#define HW 192
#define DD 512
#define GG 64
#define PP 64

typedef __attribute__((ext_vector_type(8))) short short8_t;
typedef __attribute__((ext_vector_type(4))) float floatx4;

typedef __attribute__((address_space(3))) unsigned int lds_u32;
typedef const __attribute__((address_space(1))) unsigned int glb_u32;

__device__ __forceinline__ void gload_lds16(const void* g, void* l) {
  __builtin_amdgcn_global_load_lds((glb_u32*)g, (lds_u32*)l, 16, 0, 0);
}

__device__ __forceinline__ unsigned short f2bf(float f) {
  unsigned int u = __float_as_uint(f);
  u += 0x7fffu + ((u >> 16) & 1u);
  return (unsigned short)(u >> 16);
}

// Single-pass: L2-normalize over channels + transpose + bf16 cast.
// Block = (slab, 24-pos chunk). Reads in[c][pos] coalesced, stages fp32 tile in
// LDS (pad 517 -> conflict-free both orientations), ssq computed inline,
// writes out[pos][c] bf16 coalesced (ushort2).
__global__ __launch_bounds__(384, 2) void norm_kernel(
    const float* __restrict__ gal, const float* __restrict__ prob,
    unsigned short* __restrict__ ws) {
  int b = blockIdx.x;
  int s = b >> 3;   // slab 0..127
  int q = b & 7;    // pos chunk 0..7
  const float* in = (s < GG) ? (gal + (size_t)s * DD * HW)
                             : (prob + (size_t)(s - GG) * DD * HW);
  unsigned short* out = ws + (size_t)s * DD * HW;
  int pos0 = q * 24;
  int t = threadIdx.x;
  int cq = t / 24;  // 0..15
  int pp = t % 24;  // 0..23

  __shared__ float T[24 * 517];  // ~49.6 KB
  __shared__ float sq[16][24];
  __shared__ float scl[24];

  float ssq = 0.f;
#pragma unroll 8
  for (int cb = 0; cb < 32; ++cb) {
    int c = cb * 16 + cq;
    float x = in[(size_t)c * HW + pos0 + pp];
    T[pp * 517 + c] = x;
    ssq += x * x;
  }
  sq[cq][pp] = ssq;
  __syncthreads();
  if (t < 24) {
    float v = 0.f;
#pragma unroll
    for (int r = 0; r < 16; ++r) v += sq[r][t];
    scl[t] = 1.f / fmaxf(sqrtf(v), 1e-12f);
  }
  __syncthreads();
#pragma unroll 4
  for (int k = 0; k < 16; ++k) {
    int idx2 = (t + k * 384) * 2;
    int c = idx2 & 511;
    int pp2 = idx2 >> 9;  // 0..23
    float sc = scl[pp2];
    float a = T[pp2 * 517 + c] * sc;
    float bb = T[pp2 * 517 + c + 1] * sc;
    unsigned int pk = ((unsigned)f2bf(bb) << 16) | (unsigned)f2bf(a);
    *(unsigned int*)&out[(size_t)(pos0 + pp2) * DD + c] = pk;
  }
}

// One block per (g,p): C[i][j] = sum_d kern[p][i][d]*galt[g][j][d].
// Double-buffered LDS staging: loads for kb+1 issue before compute on kb,
// so the vmcnt(0) drain at the barrier overlaps the MFMA phase.
__global__ __launch_bounds__(256, 2) void qaconv_gemm(
    const unsigned short* __restrict__ ws, const float* __restrict__ fcw,
    const float* __restrict__ bnw, const float* __restrict__ bnb,
    const float* __restrict__ bnm, const float* __restrict__ bnv,
    const float* __restrict__ fcb, const float* __restrict__ lw,
    const float* __restrict__ lb, const float* __restrict__ lm,
    const float* __restrict__ lv, float* __restrict__ out) {
  int bid = blockIdx.x;
  int sb = bid >> 6, li = bid & 63;  // 8x8 supertiles for L2 locality
  int g = ((sb >> 3) << 3) + (li >> 3);
  int p = ((sb & 7) << 3) + (li & 7);
  const unsigned short* Bsrc = ws + (size_t)g * DD * HW;         // galt[g][j][c]
  const unsigned short* Asrc = ws + (size_t)(GG + p) * DD * HW;  // kern[p][i][c]

  // chunk n = kc*192 + row, 16B per chunk -> [kc(4)][row(192)][8 bf16]
  __shared__ unsigned short A_lds[2][768 * 8];  // 2 x 12 KB
  __shared__ unsigned short B_lds[2][768 * 8];  // 2 x 12 KB
  __shared__ float colpart[2][HW];
  __shared__ float rowpart[2][HW];
  __shared__ float redbuf[4][2];

  int tid = threadIdx.x;
  int lane = tid & 63;
  int wave = tid >> 6;
  int wi = wave >> 1, wj = wave & 1;
  int l15 = lane & 15, l4 = lane >> 4;

  floatx4 acc[6][6];
#pragma unroll
  for (int a = 0; a < 6; ++a)
#pragma unroll
    for (int c = 0; c < 6; ++c) acc[a][c] = (floatx4){0.f, 0.f, 0.f, 0.f};

  // precompute per-thread staging geometry
  int sn[3], skc[3], srow[3];
#pragma unroll
  for (int s = 0; s < 3; ++s) {
    sn[s] = tid + s * 256;
    skc[s] = sn[s] / HW;
    srow[s] = sn[s] - skc[s] * HW;
  }

#define STAGE(KB, BUF)                                                  \
  do {                                                                  \
    _Pragma("unroll") for (int s_ = 0; s_ < 3; ++s_) {                  \
      size_t goff = (size_t)srow[s_] * DD + (size_t)((KB)*32 + skc[s_] * 8); \
      gload_lds16(Asrc + goff, &A_lds[BUF][sn[s_] * 8]);                \
      gload_lds16(Bsrc + goff, &B_lds[BUF][sn[s_] * 8]);                \
    }                                                                   \
  } while (0)

  STAGE(0, 0);
  __syncthreads();  // buf0 ready

  for (int kb = 0; kb < DD / 32; ++kb) {
    int cur = kb & 1;
    if (kb < DD / 32 - 1) STAGE(kb + 1, cur ^ 1);

    short8_t a[6];
#pragma unroll
    for (int it = 0; it < 6; ++it)
      a[it] = *(const short8_t*)&A_lds[cur][(l4 * HW + wi * 96 + it * 16 + l15) * 8];
#pragma unroll
    for (int jt = 0; jt < 6; ++jt) {
      short8_t b = *(const short8_t*)&B_lds[cur][(l4 * HW + wj * 96 + jt * 16 + l15) * 8];
#pragma unroll
      for (int it = 0; it < 6; ++it)
        acc[it][jt] = __builtin_amdgcn_mfma_f32_16x16x32_bf16(a[it], b, acc[it][jt], 0, 0, 0);
    }
    __syncthreads();  // drains next-buf loads (overlapped with compute above)
  }
#undef STAGE

  // ---- epilogue: dual max-pool ----
  // C/D layout: i = wi*96 + it*16 + l4*4 + r ; j = wj*96 + jt*16 + l15
  float cm[6];
  float rm[6][4];
#pragma unroll
  for (int jt = 0; jt < 6; ++jt) cm[jt] = -3.4e38f;
#pragma unroll
  for (int it = 0; it < 6; ++it)
#pragma unroll
    for (int r = 0; r < 4; ++r) rm[it][r] = -3.4e38f;
#pragma unroll
  for (int it = 0; it < 6; ++it)
#pragma unroll
    for (int jt = 0; jt < 6; ++jt)
#pragma unroll
      for (int r = 0; r < 4; ++r) {
        float v = acc[it][jt][r];
        cm[jt] = fmaxf(cm[jt], v);
        rm[it][r] = fmaxf(rm[it][r], v);
      }

#pragma unroll
  for (int jt = 0; jt < 6; ++jt) {
    float v = cm[jt];
    v = fmaxf(v, __shfl_xor(v, 16, 64));
    v = fmaxf(v, __shfl_xor(v, 32, 64));
    if (lane < 16) colpart[wi][wj * 96 + jt * 16 + lane] = v;
  }
#pragma unroll
  for (int it = 0; it < 6; ++it)
#pragma unroll
    for (int r = 0; r < 4; ++r) {
      float v = rm[it][r];
      v = fmaxf(v, __shfl_xor(v, 1, 64));
      v = fmaxf(v, __shfl_xor(v, 2, 64));
      v = fmaxf(v, __shfl_xor(v, 4, 64));
      v = fmaxf(v, __shfl_xor(v, 8, 64));
      if (l15 == 0) rowpart[wj][wi * 96 + it * 16 + l4 * 4 + r] = v;
    }
  __syncthreads();

  // ---- fused BN -> fc -> lbn -> sigmoid ----
  float part = 0.f, wpart = 0.f;
  if (tid < HW) {
    float cmax = fmaxf(colpart[0][tid], colpart[1][tid]);  // score[j]
    float rmax = fmaxf(rowpart[0][tid], rowpart[1][tid]);  // score[192+i]
    float w1 = fcw[tid], w2 = fcw[HW + tid];
    part = cmax * w1 + rmax * w2;
    wpart = w1 + w2;
  }
#pragma unroll
  for (int off = 32; off > 0; off >>= 1) {
    part += __shfl_down(part, off, 64);
    wpart += __shfl_down(wpart, off, 64);
  }
  if (lane == 0) { redbuf[wave][0] = part; redbuf[wave][1] = wpart; }
  __syncthreads();
  if (tid == 0) {
    float s = redbuf[0][0] + redbuf[1][0] + redbuf[2][0] + redbuf[3][0];
    float wsum = redbuf[0][1] + redbuf[1][1] + redbuf[2][1] + redbuf[3][1];
    float bnA = bnw[0] * rsqrtf(bnv[0] + 1e-5f);
    float bnB = bnb[0] - bnm[0] * bnA;
    float sc = bnA * s + bnB * wsum + fcb[0];
    float lA = lw[0] * rsqrtf(lv[0] + 1e-5f);
    sc = (sc - lm[0]) * lA + lb[0];
    out[g * PP + p] = 1.f / (1.f + __expf(-sc * 0.1f));
  }
}

extern "C" void kernel_launch(void* const* d_in, const int* in_sizes, int n_in,
                              void* d_out, int out_size, void* d_ws, size_t ws_size,
                              hipStream_t stream) {
  const float* gal  = (const float*)d_in[0];
  const float* prob = (const float*)d_in[1];
  const float* bnw  = (const float*)d_in[2];
  const float* bnb  = (const float*)d_in[3];
  const float* bnm  = (const float*)d_in[4];
  const float* bnv  = (const float*)d_in[5];
  const float* fcw  = (const float*)d_in[6];
  const float* fcb  = (const float*)d_in[7];
  const float* lw   = (const float*)d_in[8];
  const float* lb   = (const float*)d_in[9];
  const float* lm   = (const float*)d_in[10];
  const float* lv   = (const float*)d_in[11];
  unsigned short* ws = (unsigned short*)d_ws;
  float* out = (float*)d_out;

  hipLaunchKernelGGL(norm_kernel, dim3(1024), dim3(384), 0, stream, gal, prob, ws);
  hipLaunchKernelGGL(qaconv_gemm, dim3(GG * PP), dim3(256), 0, stream, ws, fcw,
                     bnw, bnb, bnm, bnv, fcb, lw, lb, lm, lv, out);
}

// Round 3
// 301.662 us; speedup vs baseline: 1.5680x; 1.4621x over previous
//
#include <hip/hip_runtime.h>

#define HW 192
#define DD 512
#define GG 64
#define PP 64

typedef __attribute__((ext_vector_type(8))) short short8_t;
typedef __attribute__((ext_vector_type(4))) float floatx4;

typedef __attribute__((address_space(3))) unsigned int lds_u32;
typedef const __attribute__((address_space(1))) unsigned int glb_u32;

__device__ __forceinline__ void gload_lds16(const void* g, void* l) {
  __builtin_amdgcn_global_load_lds((glb_u32*)g, (lds_u32*)l, 16, 0, 0);
}

__device__ __forceinline__ unsigned short f2bf(float f) {
  unsigned int u = __float_as_uint(f);
  u += 0x7fffu + ((u >> 16) & 1u);
  return (unsigned short)(u >> 16);
}

// Single-pass L2-normalize + transpose + bf16 cast.
// Block = (slab, 16-pos chunk), 512 threads. Pass-1 reads are full 64B aligned
// segments (16 consecutive floats per (wave-lane-group, channel)); pass-2
// writes out[pos][c] coalesced as ushort2. LDS pad 518 keeps both passes
// <=2-way on banks.
__global__ __launch_bounds__(512, 4) void norm_kernel(
    const float* __restrict__ gal, const float* __restrict__ prob,
    unsigned short* __restrict__ ws) {
  int b = blockIdx.x;  // 0..1535
  int s = b / 12;      // slab 0..127
  int q = b - s * 12;  // pos chunk 0..11
  const float* in = (s < GG) ? (gal + (size_t)s * DD * HW)
                             : (prob + (size_t)(s - GG) * DD * HW);
  unsigned short* out = ws + (size_t)s * DD * HW;
  int pos0 = q * 16;
  int t = threadIdx.x;
  int cq = t >> 4;  // 0..31
  int pp = t & 15;  // 0..15

  __shared__ float T[16 * 518];  // 33.2 KB
  __shared__ float sq[32][16];
  __shared__ float scl[16];

  float ssq = 0.f;
#pragma unroll 4
  for (int cb = 0; cb < 16; ++cb) {
    int c = cb * 32 + cq;
    float x = in[(size_t)c * HW + pos0 + pp];
    T[pp * 518 + c] = x;
    ssq += x * x;
  }
  sq[cq][pp] = ssq;
  __syncthreads();
  if (t < 16) {
    float v = 0.f;
#pragma unroll
    for (int r = 0; r < 32; ++r) v += sq[r][t];
    scl[t] = 1.f / fmaxf(sqrtf(v), 1e-12f);
  }
  __syncthreads();
#pragma unroll
  for (int k = 0; k < 8; ++k) {
    int idx2 = (t + k * 512) * 2;
    int c = idx2 & 511;
    int pp2 = idx2 >> 9;  // 0..15
    float sc = scl[pp2];
    float a = T[pp2 * 518 + c] * sc;
    float bb = T[pp2 * 518 + c + 1] * sc;
    unsigned int pk = ((unsigned)f2bf(bb) << 16) | (unsigned)f2bf(a);
    *(unsigned int*)&out[(size_t)(pos0 + pp2) * DD + c] = pk;
  }
}

// One block per (g,p): C[i][j] = sum_d kern[p][i][d]*galt[g][j][d].
// Staging: lane l of a wave-instruction covers (row = l/4, kc-chunk) so each
// instruction touches 16 FULL 64B lines (was: 64 lines x 16B -> request-rate
// bound, MfmaUtil 18%). LDS layout forced to [row][slot] by the
// uniform-base+lane*16 rule; global kc is XOR-swizzled per lane
// (kc = (l&3)^((l>>3)&3)) so fragment ds_read_b128 phases land 2-way on
// banks (free, m136). Double-buffered so the vmcnt drain overlaps MFMA.
__global__ __launch_bounds__(256, 2) void qaconv_gemm(
    const unsigned short* __restrict__ ws, const float* __restrict__ fcw,
    const float* __restrict__ bnw, const float* __restrict__ bnb,
    const float* __restrict__ bnm, const float* __restrict__ bnv,
    const float* __restrict__ fcb, const float* __restrict__ lw,
    const float* __restrict__ lb, const float* __restrict__ lm,
    const float* __restrict__ lv, float* __restrict__ out) {
  int bid = blockIdx.x;
  int sb = bid >> 6, li = bid & 63;  // 8x8 supertiles for L2 locality
  int g = ((sb >> 3) << 3) + (li >> 3);
  int p = ((sb & 7) << 3) + (li & 7);
  const unsigned short* Bsrc = ws + (size_t)g * DD * HW;         // galt[g][j][c]
  const unsigned short* Asrc = ws + (size_t)(GG + p) * DD * HW;  // kern[p][i][c]

  // LDS: slot n = row*4 + ((kc) ^ ((row>>1)&3)), 16B per slot
  __shared__ unsigned short A_lds[2][768 * 8];  // 2 x 12 KB
  __shared__ unsigned short B_lds[2][768 * 8];  // 2 x 12 KB
  __shared__ float colpart[2][HW];
  __shared__ float rowpart[2][HW];
  __shared__ float redbuf[4][2];

  int tid = threadIdx.x;
  int lane = tid & 63;
  int wave = tid >> 6;
  int wi = wave >> 1, wj = wave & 1;
  int l15 = lane & 15, l4 = lane >> 4;

  floatx4 acc[6][6];
#pragma unroll
  for (int a = 0; a < 6; ++a)
#pragma unroll
    for (int c = 0; c < 6; ++c) acc[a][c] = (floatx4){0.f, 0.f, 0.f, 0.f};

  // staging geometry: n = tid + s*256; row = n>>2; kc = (n&3)^((n>>3)&3)
  int sn[3];
  size_t sbase[3];
#pragma unroll
  for (int s = 0; s < 3; ++s) {
    int n = tid + s * 256;
    int r = n >> 2;
    int kc = (n & 3) ^ ((n >> 3) & 3);
    sn[s] = n;
    sbase[s] = (size_t)r * DD + (size_t)(kc * 8);
  }

#define STAGE(KB, BUF)                                   \
  do {                                                   \
    _Pragma("unroll") for (int s_ = 0; s_ < 3; ++s_) {   \
      size_t goff = sbase[s_] + (size_t)((KB)*32);       \
      gload_lds16(Asrc + goff, &A_lds[BUF][sn[s_] * 8]); \
      gload_lds16(Bsrc + goff, &B_lds[BUF][sn[s_] * 8]); \
    }                                                    \
  } while (0)

  STAGE(0, 0);
  __syncthreads();  // buf0 ready

  // fragment slot bases: slot = (row*4 + (l4 ^ ((row>>1)&3))) ; row = w*96+it*16+l15
  // (row>>1)&3 == (l15>>1)&3 since w*96+it*16 is a multiple of 4 after >>1... (16/2=8, 96/2=48, both %4==0)
  int sw = l4 ^ ((l15 >> 1) & 3);
  int aBase = ((wi * 96 + l15) * 4 + sw) * 8;
  int bBase = ((wj * 96 + l15) * 4 + sw) * 8;

  for (int kb = 0; kb < DD / 32; ++kb) {
    int cur = kb & 1;
    if (kb < DD / 32 - 1) STAGE(kb + 1, cur ^ 1);

    short8_t a[6];
#pragma unroll
    for (int it = 0; it < 6; ++it)
      a[it] = *(const short8_t*)&A_lds[cur][aBase + it * 512];
#pragma unroll
    for (int jt = 0; jt < 6; ++jt) {
      short8_t b = *(const short8_t*)&B_lds[cur][bBase + jt * 512];
#pragma unroll
      for (int it = 0; it < 6; ++it)
        acc[it][jt] = __builtin_amdgcn_mfma_f32_16x16x32_bf16(a[it], b, acc[it][jt], 0, 0, 0);
    }
    __syncthreads();
  }
#undef STAGE

  // ---- epilogue: dual max-pool ----
  // C/D layout: i = wi*96 + it*16 + l4*4 + r ; j = wj*96 + jt*16 + l15
  float cm[6];
  float rm[6][4];
#pragma unroll
  for (int jt = 0; jt < 6; ++jt) cm[jt] = -3.4e38f;
#pragma unroll
  for (int it = 0; it < 6; ++it)
#pragma unroll
    for (int r = 0; r < 4; ++r) rm[it][r] = -3.4e38f;
#pragma unroll
  for (int it = 0; it < 6; ++it)
#pragma unroll
    for (int jt = 0; jt < 6; ++jt)
#pragma unroll
      for (int r = 0; r < 4; ++r) {
        float v = acc[it][jt][r];
        cm[jt] = fmaxf(cm[jt], v);
        rm[it][r] = fmaxf(rm[it][r], v);
      }

#pragma unroll
  for (int jt = 0; jt < 6; ++jt) {
    float v = cm[jt];
    v = fmaxf(v, __shfl_xor(v, 16, 64));
    v = fmaxf(v, __shfl_xor(v, 32, 64));
    if (lane < 16) colpart[wi][wj * 96 + jt * 16 + lane] = v;
  }
#pragma unroll
  for (int it = 0; it < 6; ++it)
#pragma unroll
    for (int r = 0; r < 4; ++r) {
      float v = rm[it][r];
      v = fmaxf(v, __shfl_xor(v, 1, 64));
      v = fmaxf(v, __shfl_xor(v, 2, 64));
      v = fmaxf(v, __shfl_xor(v, 4, 64));
      v = fmaxf(v, __shfl_xor(v, 8, 64));
      if (l15 == 0) rowpart[wj][wi * 96 + it * 16 + l4 * 4 + r] = v;
    }
  __syncthreads();

  // ---- fused BN -> fc -> lbn -> sigmoid ----
  float part = 0.f, wpart = 0.f;
  if (tid < HW) {
    float cmax = fmaxf(colpart[0][tid], colpart[1][tid]);  // score[j]
    float rmax = fmaxf(rowpart[0][tid], rowpart[1][tid]);  // score[192+i]
    float w1 = fcw[tid], w2 = fcw[HW + tid];
    part = cmax * w1 + rmax * w2;
    wpart = w1 + w2;
  }
#pragma unroll
  for (int off = 32; off > 0; off >>= 1) {
    part += __shfl_down(part, off, 64);
    wpart += __shfl_down(wpart, off, 64);
  }
  if (lane == 0) { redbuf[wave][0] = part; redbuf[wave][1] = wpart; }
  __syncthreads();
  if (tid == 0) {
    float s = redbuf[0][0] + redbuf[1][0] + redbuf[2][0] + redbuf[3][0];
    float wsum = redbuf[0][1] + redbuf[1][1] + redbuf[2][1] + redbuf[3][1];
    float bnA = bnw[0] * rsqrtf(bnv[0] + 1e-5f);
    float bnB = bnb[0] - bnm[0] * bnA;
    float sc = bnA * s + bnB * wsum + fcb[0];
    float lA = lw[0] * rsqrtf(lv[0] + 1e-5f);
    sc = (sc - lm[0]) * lA + lb[0];
    out[g * PP + p] = 1.f / (1.f + __expf(-sc * 0.1f));
  }
}

extern "C" void kernel_launch(void* const* d_in, const int* in_sizes, int n_in,
                              void* d_out, int out_size, void* d_ws, size_t ws_size,
                              hipStream_t stream) {
  const float* gal  = (const float*)d_in[0];
  const float* prob = (const float*)d_in[1];
  const float* bnw  = (const float*)d_in[2];
  const float* bnb  = (const float*)d_in[3];
  const float* bnm  = (const float*)d_in[4];
  const float* bnv  = (const float*)d_in[5];
  const float* fcw  = (const float*)d_in[6];
  const float* fcb  = (const float*)d_in[7];
  const float* lw   = (const float*)d_in[8];
  const float* lb   = (const float*)d_in[9];
  const float* lm   = (const float*)d_in[10];
  const float* lv   = (const float*)d_in[11];
  unsigned short* ws = (unsigned short*)d_ws;
  float* out = (float*)d_out;

  hipLaunchKernelGGL(norm_kernel, dim3(1536), dim3(512), 0, stream, gal, prob, ws);
  hipLaunchKernelGGL(qaconv_gemm, dim3(GG * PP), dim3(256), 0, stream, ws, fcw,
                     bnw, bnb, bnm, bnv, fcb, lw, lb, lm, lv, out);
}